// Round 2
// baseline (630.117 us; speedup 1.0000x reference)
//
#include <hip/hip_runtime.h>
#include <hip/hip_bf16.h>

#define NPTS 262144
#define DDIM 64
#define KCB  1024

__global__ __launch_bounds__(256) void c2_kernel(const float* __restrict__ cb,
                                                 float* __restrict__ c2) {
    int k = blockIdx.x * blockDim.x + threadIdx.x;
    if (k >= KCB) return;
    const float4* row = (const float4*)(cb + (size_t)k * DDIM);
    float s0 = 0.f, s1 = 0.f, s2 = 0.f, s3 = 0.f;
#pragma unroll
    for (int j = 0; j < DDIM / 4; ++j) {
        float4 a = row[j];
        s0 = __builtin_fmaf(a.x, a.x, s0);
        s1 = __builtin_fmaf(a.y, a.y, s1);
        s2 = __builtin_fmaf(a.z, a.z, s2);
        s3 = __builtin_fmaf(a.w, a.w, s3);
    }
    c2[k] = (s0 + s1) + (s2 + s3);
}

__global__ __launch_bounds__(256) void vq_kernel(const float* __restrict__ x,
                                                 const float* __restrict__ cb,
                                                 const float* __restrict__ c2,
                                                 float* __restrict__ out) {
    const int i = blockIdx.x * 256 + threadIdx.x;

    // This thread's point (64 f32) in VGPRs.
    float4 xr[16];
    const float4* xp = (const float4*)(x + (size_t)i * DDIM);
#pragma unroll
    for (int j = 0; j < 16; ++j) xr[j] = xp[j];

    float best = 3.402823466e+38f;
    int bestk = 0;

    // k is wave-uniform; readfirstlane makes that explicit so codebook reads
    // lower to s_load (SMEM) and the dot is v_fmac_f32 with SGPR operands.
    for (int k = 0; k < KCB; ++k) {
        const int ku = __builtin_amdgcn_readfirstlane(k);
        const float* c = cb + (size_t)ku * DDIM;
        float d0 = 0.f, d1 = 0.f, d2 = 0.f, d3 = 0.f;
#pragma unroll
        for (int j = 0; j < 16; ++j) {
            d0 = __builtin_fmaf(xr[j].x, c[4 * j + 0], d0);
            d1 = __builtin_fmaf(xr[j].y, c[4 * j + 1], d1);
            d2 = __builtin_fmaf(xr[j].z, c[4 * j + 2], d2);
            d3 = __builtin_fmaf(xr[j].w, c[4 * j + 3], d3);
        }
        float dot = (d0 + d1) + (d2 + d3);
        // argmin of ||x||^2 + ||c||^2 - 2 x.c  ==  argmin of c2[k] - 2*dot
        float score = __builtin_fmaf(-2.f, dot, c2[ku]);
        if (score < best) { best = score; bestk = ku; }  // strict < => first index on ties
    }

    // Output layout (f32 elements): encoded[N], then quantized[N*64].
    out[i] = (float)bestk;

    const float4* cr = (const float4*)(cb + (size_t)bestk * DDIM);
    float4* q = (float4*)(out + NPTS + (size_t)i * DDIM);
#pragma unroll
    for (int j = 0; j < 16; ++j) q[j] = cr[j];
}

extern "C" void kernel_launch(void* const* d_in, const int* in_sizes, int n_in,
                              void* d_out, int out_size, void* d_ws, size_t ws_size,
                              hipStream_t stream) {
    const float* x  = (const float*)d_in[0];
    const float* cb = (const float*)d_in[1];
    float* c2 = (float*)d_ws;  // KCB floats of scratch

    hipLaunchKernelGGL(c2_kernel, dim3(KCB / 256), dim3(256), 0, stream, cb, c2);
    hipLaunchKernelGGL(vq_kernel, dim3(NPTS / 256), dim3(256), 0, stream,
                       x, cb, c2, (float*)d_out);
}

// Round 3
// 239.953 us; speedup vs baseline: 2.6260x; 2.6260x over previous
//
#include <hip/hip_runtime.h>
#include <hip/hip_bf16.h>

#define NPTS 262144
#define DDIM 64
#define KCB  1024
#define CHUNK 128            // codebook rows staged in LDS per iteration
#define NCHUNK (KCB / CHUNK) // 8
#define GROUPS (CHUNK / 16)  // 8 groups of 16 codebook cols per chunk

typedef __attribute__((ext_vector_type(8))) short short8;
typedef __attribute__((ext_vector_type(4))) float f32x4;

static __device__ __forceinline__ unsigned short f2bf_rne(float f) {
    union { float f; unsigned u; } v; v.f = f;
    unsigned r = v.u + 0x7FFFu + ((v.u >> 16) & 1u);
    return (unsigned short)(r >> 16);
}
static __device__ __forceinline__ float bf2f(unsigned short h) {
    union { unsigned u; float f; } v; v.u = ((unsigned)h) << 16;
    return v.f;
}
// "a beats b" in acc-space (maximize), ties -> lower index (matches argmin-first)
static __device__ __forceinline__ bool beats(float sa, int ka, float sb, int kb) {
    return (sa > sb) || (sa == sb && ka < kb);
}

__global__ __launch_bounds__(256) void c2n_kernel(const float* __restrict__ cb,
                                                  float* __restrict__ c2n) {
    int k = blockIdx.x * blockDim.x + threadIdx.x;
    if (k >= KCB) return;
    const float4* row = (const float4*)(cb + (size_t)k * DDIM);
    float s0 = 0.f, s1 = 0.f, s2 = 0.f, s3 = 0.f;
#pragma unroll
    for (int j = 0; j < DDIM / 4; ++j) {
        float4 a = row[j];
        s0 = __builtin_fmaf(a.x, a.x, s0);
        s1 = __builtin_fmaf(a.y, a.y, s1);
        s2 = __builtin_fmaf(a.z, a.z, s2);
        s3 = __builtin_fmaf(a.w, a.w, s3);
    }
    c2n[k] = -0.5f * ((s0 + s1) + (s2 + s3));
}

__global__ __launch_bounds__(256, 2) void vq_mfma(const float* __restrict__ x,
                                                  const float* __restrict__ cb,
                                                  const float* __restrict__ c2n,
                                                  float* __restrict__ out) {
    // LDS: codebook chunk as bf16 hi/lo, slot-XOR swizzled; c2n chunk; result staging
    __shared__ unsigned short lds_hi[CHUNK * 64];
    __shared__ unsigned short lds_lo[CHUNK * 64];
    __shared__ float lds_c2[CHUNK];
    __shared__ int lds_bk1[256];
    __shared__ int lds_bk2[256];

    const int tid = threadIdx.x;
    const int lane = tid & 63;
    const int wave = tid >> 6;
    const int b15 = lane & 15;   // MFMA col (cb) / A row (point) selector
    const int q = lane >> 4;     // k-quadrant: lane supplies k = q*8..q*8+7
    const int blk_base = blockIdx.x * 256;
    const int wave_base = blk_base + wave * 64;

    // ---- A fragments: 4 point-tiles x 2 ksteps x (hi,lo), resident all kernel ----
    // A[row][k]: lane holds row = b15 (of tile), k = ks*32 + q*8 + j (j=0..7)
    short8 Ahi[4][2], Alo[4][2];
#pragma unroll
    for (int t = 0; t < 4; ++t) {
        const float* xr = x + (size_t)(wave_base + t * 16 + b15) * DDIM + q * 8;
#pragma unroll
        for (int ks = 0; ks < 2; ++ks) {
            float4 v0 = *(const float4*)(xr + ks * 32);
            float4 v1 = *(const float4*)(xr + ks * 32 + 4);
            float vv[8] = {v0.x, v0.y, v0.z, v0.w, v1.x, v1.y, v1.z, v1.w};
            short8 h, l;
#pragma unroll
            for (int j = 0; j < 8; ++j) {
                unsigned short hb = f2bf_rne(vv[j]);
                h[j] = (short)hb;
                l[j] = (short)f2bf_rne(vv[j] - bf2f(hb));
            }
            Ahi[t][ks] = h;
            Alo[t][ks] = l;
        }
    }

    // top-2 tracking per lane: 16 points (4 tiles x 4 acc rows)
    float best1[16], best2[16];
    int bk1[16], bk2[16];
#pragma unroll
    for (int i = 0; i < 16; ++i) {
        best1[i] = -3.402823466e+38f; best2[i] = -3.402823466e+38f;
        bk1[i] = 0; bk2[i] = 0;
    }

    for (int c = 0; c < NCHUNK; ++c) {
        __syncthreads();
        // ---- stage chunk: 256 threads, 128 rows, 2 half-rows each ----
        {
            int r = tid & 127, hh = tid >> 7;
            const float* src = cb + (size_t)(c * CHUNK + r) * DDIM + hh * 32;
#pragma unroll
            for (int s4 = 0; s4 < 4; ++s4) {
                int s = hh * 4 + s4;  // slot = d/8
                float4 v0 = ((const float4*)src)[s4 * 2 + 0];
                float4 v1 = ((const float4*)src)[s4 * 2 + 1];
                float vv[8] = {v0.x, v0.y, v0.z, v0.w, v1.x, v1.y, v1.z, v1.w};
                short8 h, l;
#pragma unroll
                for (int j = 0; j < 8; ++j) {
                    unsigned short hb = f2bf_rne(vv[j]);
                    h[j] = (short)hb;
                    l[j] = (short)f2bf_rne(vv[j] - bf2f(hb));
                }
                int idx = r * 64 + ((s ^ (r & 7)) << 3);  // slot-XOR swizzle
                *(short8*)(lds_hi + idx) = h;
                *(short8*)(lds_lo + idx) = l;
            }
            if (tid < CHUNK) lds_c2[tid] = c2n[c * CHUNK + tid];
        }
        __syncthreads();

        // ---- K-loop over 16-col groups ----
        for (int g = 0; g < GROUPS; ++g) {
            const int cbl = g * 16 + b15;          // local cb row this lane reads
            const int kglob = c * CHUNK + cbl;     // its global index
            const float cinit = lds_c2[cbl];       // -0.5*||c||^2 -> acc init
            f32x4 acc[4];
#pragma unroll
            for (int t = 0; t < 4; ++t) acc[t] = (f32x4){cinit, cinit, cinit, cinit};

#pragma unroll
            for (int ks = 0; ks < 2; ++ks) {
                int s = ks * 4 + q;
                int idx = cbl * 64 + ((s ^ (cbl & 7)) << 3);
                short8 Bhi = *(const short8*)(lds_hi + idx);
                short8 Blo = *(const short8*)(lds_lo + idx);
#pragma unroll
                for (int t = 0; t < 4; ++t) {
                    acc[t] = __builtin_amdgcn_mfma_f32_16x16x32_bf16(Ahi[t][ks], Bhi, acc[t], 0, 0, 0);
                    acc[t] = __builtin_amdgcn_mfma_f32_16x16x32_bf16(Ahi[t][ks], Blo, acc[t], 0, 0, 0);
                    acc[t] = __builtin_amdgcn_mfma_f32_16x16x32_bf16(Alo[t][ks], Bhi, acc[t], 0, 0, 0);
                }
            }
            // ---- top-2 update (k ascending: strict > keeps lowest index) ----
#pragma unroll
            for (int t = 0; t < 4; ++t) {
#pragma unroll
                for (int r = 0; r < 4; ++r) {
                    int i = t * 4 + r;
                    float s = acc[t][r];
                    bool gt1 = s > best1[i];
                    bool gt2 = s > best2[i];
                    best2[i] = gt1 ? best1[i] : (gt2 ? s : best2[i]);
                    bk2[i]   = gt1 ? bk1[i]   : (gt2 ? kglob : bk2[i]);
                    best1[i] = gt1 ? s : best1[i];
                    bk1[i]   = gt1 ? kglob : bk1[i];
                }
            }
        }
    }

    // ---- cross-lane top-2 merge within each 16-lane group (cols 0..15) ----
#pragma unroll
    for (int m = 1; m < 16; m <<= 1) {
#pragma unroll
        for (int i = 0; i < 16; ++i) {
            float o1 = __shfl_xor(best1[i], m);
            int ok1 = __shfl_xor(bk1[i], m);
            float o2 = __shfl_xor(best2[i], m);
            int ok2 = __shfl_xor(bk2[i], m);
            float n1, n2; int nk1, nk2;
            if (beats(o1, ok1, best1[i], bk1[i])) {
                n1 = o1; nk1 = ok1;
                if (beats(best1[i], bk1[i], o2, ok2)) { n2 = best1[i]; nk2 = bk1[i]; }
                else { n2 = o2; nk2 = ok2; }
            } else {
                n1 = best1[i]; nk1 = bk1[i];
                if (beats(o1, ok1, best2[i], bk2[i])) { n2 = o1; nk2 = ok1; }
                else { n2 = best2[i]; nk2 = bk2[i]; }
            }
            best1[i] = n1; bk1[i] = nk1; best2[i] = n2; bk2[i] = nk2;
        }
    }

    // ---- stage per-point candidates to LDS (one writer lane per 16-lane group) ----
    __syncthreads();  // chunk LDS no longer needed; also orders prior reads
    if (b15 == 0) {
#pragma unroll
        for (int t = 0; t < 4; ++t)
#pragma unroll
            for (int r = 0; r < 4; ++r) {
                int pl = wave * 64 + t * 16 + q * 4 + r;
                lds_bk1[pl] = bk1[t * 4 + r];
                lds_bk2[pl] = bk2[t * 4 + r];
            }
    }
    __syncthreads();

    // ---- exact f32 re-rank of the two candidates + output ----
    const int p = blk_base + tid;  // one point per thread (256 points/block)
    const int k1 = lds_bk1[tid], k2 = lds_bk2[tid];
    const float4* xr = (const float4*)(x + (size_t)p * DDIM);
    const float4* c1 = (const float4*)(cb + (size_t)k1 * DDIM);
    const float4* c2r = (const float4*)(cb + (size_t)k2 * DDIM);
    float d1a = 0.f, d1b = 0.f, d2a = 0.f, d2b = 0.f;
#pragma unroll
    for (int j = 0; j < 16; ++j) {
        float4 xv = xr[j];
        float4 u = c1[j], w = c2r[j];
        d1a = __builtin_fmaf(xv.x, u.x, d1a); d1b = __builtin_fmaf(xv.y, u.y, d1b);
        d1a = __builtin_fmaf(xv.z, u.z, d1a); d1b = __builtin_fmaf(xv.w, u.w, d1b);
        d2a = __builtin_fmaf(xv.x, w.x, d2a); d2b = __builtin_fmaf(xv.y, w.y, d2b);
        d2a = __builtin_fmaf(xv.z, w.z, d2a); d2b = __builtin_fmaf(xv.w, w.w, d2b);
    }
    float a1 = (d1a + d1b) + c2n[k1];
    float a2 = (d2a + d2b) + c2n[k2];
    int kf = beats(a1, k1, a2, k2) ? k1 : k2;

    out[p] = (float)kf;
    const float4* cf = (const float4*)(cb + (size_t)kf * DDIM);
    float4* qo = (float4*)(out + NPTS + (size_t)p * DDIM);
#pragma unroll
    for (int j = 0; j < 16; ++j) qo[j] = cf[j];
}

extern "C" void kernel_launch(void* const* d_in, const int* in_sizes, int n_in,
                              void* d_out, int out_size, void* d_ws, size_t ws_size,
                              hipStream_t stream) {
    const float* x = (const float*)d_in[0];
    const float* cb = (const float*)d_in[1];
    float* c2n = (float*)d_ws;  // KCB floats

    hipLaunchKernelGGL(c2n_kernel, dim3(KCB / 256), dim3(256), 0, stream, cb, c2n);
    hipLaunchKernelGGL(vq_mfma, dim3(NPTS / 256), dim3(256), 0, stream,
                       x, cb, c2n, (float*)d_out);
}

// Round 4
// 169.045 us; speedup vs baseline: 3.7275x; 1.4195x over previous
//
#include <hip/hip_runtime.h>
#include <hip/hip_bf16.h>

#define NPTS 262144
#define DDIM 64
#define KCB  1024
#define CHUNK 128            // codebook rows per staged chunk
#define NCHUNK (KCB / CHUNK) // 8
#define GPC (CHUNK / 16)     // 8 groups (16 cols) per chunk

typedef __attribute__((ext_vector_type(8))) short short8;
typedef __attribute__((ext_vector_type(4))) float f32x4;

static __device__ __forceinline__ unsigned short f2bf_rne(float f) {
    union { float f; unsigned u; } v; v.f = f;
    unsigned r = v.u + 0x7FFFu + ((v.u >> 16) & 1u);
    return (unsigned short)(r >> 16);
}
static __device__ __forceinline__ float bf2f(unsigned short h) {
    union { unsigned u; float f; } v; v.u = ((unsigned)h) << 16;
    return v.f;
}
static __device__ __forceinline__ bool beats(float sa, int ka, float sb, int kb) {
    return (sa > sb) || (sa == sb && ka < kb);
}

// prep 1: c2n[k] = 256 - 0.5*||c||^2  (shift makes all scores positive ->
// f32 bit pattern is monotone as u32; argmax acc == argmin distance)
__global__ __launch_bounds__(256) void c2n_kernel(const float* __restrict__ cb,
                                                  float* __restrict__ c2n) {
    int k = blockIdx.x * blockDim.x + threadIdx.x;
    if (k >= KCB) return;
    const float4* row = (const float4*)(cb + (size_t)k * DDIM);
    float s0 = 0.f, s1 = 0.f, s2 = 0.f, s3 = 0.f;
#pragma unroll
    for (int j = 0; j < DDIM / 4; ++j) {
        float4 a = row[j];
        s0 = __builtin_fmaf(a.x, a.x, s0);
        s1 = __builtin_fmaf(a.y, a.y, s1);
        s2 = __builtin_fmaf(a.z, a.z, s2);
        s3 = __builtin_fmaf(a.w, a.w, s3);
    }
    c2n[k] = 256.0f - 0.5f * ((s0 + s1) + (s2 + s3));
}

// prep 2: pack codebook into bf16 hi/lo fragment-layout image.
// Chunk c (128 rows): ushort[16384] = [hi 8192][lo 8192];
// within: idx = g*1024 + ks*512 + q*128 + col*8 + j
//   (row = c*128 + g*16 + col, dim d = ks*32 + q*8 + j)
// => B-fragment read for lane l is lds_byte = g*2048 + ks*1024 + l*16 (+16384 for lo)
__global__ __launch_bounds__(256) void pack_kernel(const float* __restrict__ cb,
                                                   unsigned short* __restrict__ G) {
    int t = blockIdx.x * 256 + threadIdx.x;  // 8192 threads: (row, d8)
    int r = t >> 3, d8 = t & 7;
    const float4* src = (const float4*)(cb + (size_t)r * DDIM + d8 * 8);
    float4 v0 = src[0], v1 = src[1];
    float vv[8] = {v0.x, v0.y, v0.z, v0.w, v1.x, v1.y, v1.z, v1.w};
    short8 h, l;
#pragma unroll
    for (int j = 0; j < 8; ++j) {
        unsigned short hb = f2bf_rne(vv[j]);
        h[j] = (short)hb;
        l[j] = (short)f2bf_rne(vv[j] - bf2f(hb));
    }
    int c = r >> 7, g = (r >> 4) & 7, col = r & 15;
    int ks = d8 >> 2, q = d8 & 3;
    size_t base = (size_t)c * 16384 + g * 1024 + ks * 512 + q * 128 + col * 8;
    *(short8*)(G + base) = h;
    *(short8*)(G + base + 8192) = l;
}

__global__ __launch_bounds__(256, 2) void vq_main(const float* __restrict__ x,
                                                  const float* __restrict__ cb,
                                                  const float* __restrict__ c2n,
                                                  const unsigned short* __restrict__ G,
                                                  float* __restrict__ out) {
    __shared__ unsigned short frag[CHUNK * DDIM * 2];  // 32 KB chunk image
    __shared__ int lds_bk1[256];
    __shared__ int lds_bk2[256];

    const int tid = threadIdx.x;
    const int lane = tid & 63;
    const int wave = tid >> 6;
    const int b15 = lane & 15;
    const int q = lane >> 4;
    const int blk_base = blockIdx.x * 256;
    const int wave_base = blk_base + wave * 64;

    // ---- A fragments (hi/lo bf16 of this wave's 64 points), resident ----
    short8 Ahi[4][2], Alo[4][2];
#pragma unroll
    for (int t = 0; t < 4; ++t) {
        const float* xr = x + (size_t)(wave_base + t * 16 + b15) * DDIM + q * 8;
#pragma unroll
        for (int ks = 0; ks < 2; ++ks) {
            float4 v0 = *(const float4*)(xr + ks * 32);
            float4 v1 = *(const float4*)(xr + ks * 32 + 4);
            float vv[8] = {v0.x, v0.y, v0.z, v0.w, v1.x, v1.y, v1.z, v1.w};
            short8 h, l;
#pragma unroll
            for (int j = 0; j < 8; ++j) {
                unsigned short hb = f2bf_rne(vv[j]);
                h[j] = (short)hb;
                l[j] = (short)f2bf_rne(vv[j] - bf2f(hb));
            }
            Ahi[t][ks] = h;
            Alo[t][ks] = l;
        }
    }

    // packed-key top-2 per point (16 points/lane); keys are positive-f32 bits
    // with low 6 bits = (63 - group_id)  -> ties prefer lower group (lower k)
    unsigned int b1[16], b2[16];
#pragma unroll
    for (int i = 0; i < 16; ++i) { b1[i] = 0u; b2[i] = 0u; }

    const int lane_off = lane * 16;  // byte offset of this lane's fragment slot

    for (int c = 0; c < NCHUNK; ++c) {
        __syncthreads();
        // stage 32KB chunk: pure async copy, linear (layout pre-packed in G)
        {
            const unsigned char* gsrc = (const unsigned char*)G + (size_t)c * 32768 + wave * 1024 + lane * 16;
            unsigned char* ldst = (unsigned char*)frag + wave * 1024;
#pragma unroll
            for (int it = 0; it < 8; ++it) {
                __builtin_amdgcn_global_load_lds(
                    (const __attribute__((address_space(1))) unsigned int*)(gsrc + it * 4096),
                    (__attribute__((address_space(3))) unsigned int*)(ldst + it * 4096),
                    16, 0, 0);
            }
        }
        // per-chunk acc-init values (L2-hit loads, latency hidden by barrier)
        float c2v[GPC];
#pragma unroll
        for (int g = 0; g < GPC; ++g) c2v[g] = c2n[c * CHUNK + g * 16 + b15];
        __syncthreads();

#pragma unroll
        for (int g = 0; g < GPC; ++g) {
            f32x4 acc[4];
#pragma unroll
            for (int t = 0; t < 4; ++t) acc[t] = (f32x4){c2v[g], c2v[g], c2v[g], c2v[g]};
#pragma unroll
            for (int ks = 0; ks < 2; ++ks) {
                const short8 Bhi = *(const short8*)((const unsigned char*)frag + g * 2048 + ks * 1024 + lane_off);
                const short8 Blo = *(const short8*)((const unsigned char*)frag + 16384 + g * 2048 + ks * 1024 + lane_off);
#pragma unroll
                for (int t = 0; t < 4; ++t) {
                    acc[t] = __builtin_amdgcn_mfma_f32_16x16x32_bf16(Ahi[t][ks], Bhi, acc[t], 0, 0, 0);
                    acc[t] = __builtin_amdgcn_mfma_f32_16x16x32_bf16(Ahi[t][ks], Blo, acc[t], 0, 0, 0);
                    acc[t] = __builtin_amdgcn_mfma_f32_16x16x32_bf16(Alo[t][ks], Bhi, acc[t], 0, 0, 0);
                }
            }
            const unsigned int inv = 63u - (unsigned)(c * GPC + g);
#pragma unroll
            for (int t = 0; t < 4; ++t) {
#pragma unroll
                for (int r = 0; r < 4; ++r) {
                    int i = t * 4 + r;
                    unsigned int kb = (__float_as_uint(acc[t][r]) & 0xFFFFFFC0u) | inv;
                    unsigned int mn = b1[i] < kb ? b1[i] : kb;
                    b1[i] = b1[i] > kb ? b1[i] : kb;
                    b2[i] = b2[i] > mn ? b2[i] : mn;
                }
            }
        }
    }

    // ---- decode candidate k before cross-lane merge (k needs source lane's b15) ----
    unsigned int K1[16], K2[16];
    int I1[16], I2[16];
#pragma unroll
    for (int i = 0; i < 16; ++i) {
        K1[i] = b1[i]; I1[i] = (int)(63u - (b1[i] & 63u)) * 16 + b15;
        K2[i] = b2[i]; I2[i] = (int)(63u - (b2[i] & 63u)) * 16 + b15;
    }
    // merge top-2 across the 16 col-lanes of each quadrant
#pragma unroll
    for (int m = 1; m < 16; m <<= 1) {
#pragma unroll
        for (int i = 0; i < 16; ++i) {
            unsigned int o1 = __shfl_xor(K1[i], m); int oi1 = __shfl_xor(I1[i], m);
            unsigned int o2 = __shfl_xor(K2[i], m); int oi2 = __shfl_xor(I2[i], m);
            bool ob = (o1 > K1[i]) || (o1 == K1[i] && oi1 < I1[i]);
            unsigned int nk1, nk2; int ni1, ni2;
            if (ob) {
                nk1 = o1; ni1 = oi1;
                bool sb = (K1[i] > o2) || (K1[i] == o2 && I1[i] < oi2);
                nk2 = sb ? K1[i] : o2; ni2 = sb ? I1[i] : oi2;
            } else {
                nk1 = K1[i]; ni1 = I1[i];
                bool sb = (o1 > K2[i]) || (o1 == K2[i] && oi1 < I2[i]);
                nk2 = sb ? o1 : K2[i]; ni2 = sb ? oi1 : I2[i];
            }
            K1[i] = nk1; I1[i] = ni1; K2[i] = nk2; I2[i] = ni2;
        }
    }

    __syncthreads();
    if (b15 == 0) {
#pragma unroll
        for (int t = 0; t < 4; ++t)
#pragma unroll
            for (int r = 0; r < 4; ++r) {
                int pl = wave * 64 + t * 16 + q * 4 + r;
                lds_bk1[pl] = I1[t * 4 + r];
                lds_bk2[pl] = I2[t * 4 + r];
            }
    }
    __syncthreads();

    // ---- exact f32 re-rank of the two candidates + output (proven in r3) ----
    const int p = blk_base + tid;
    const int k1 = lds_bk1[tid], k2 = lds_bk2[tid];
    const float4* xr = (const float4*)(x + (size_t)p * DDIM);
    const float4* c1 = (const float4*)(cb + (size_t)k1 * DDIM);
    const float4* c2r = (const float4*)(cb + (size_t)k2 * DDIM);
    float d1a = 0.f, d1b = 0.f, d2a = 0.f, d2b = 0.f;
#pragma unroll
    for (int j = 0; j < 16; ++j) {
        float4 xv = xr[j];
        float4 u = c1[j], w = c2r[j];
        d1a = __builtin_fmaf(xv.x, u.x, d1a); d1b = __builtin_fmaf(xv.y, u.y, d1b);
        d1a = __builtin_fmaf(xv.z, u.z, d1a); d1b = __builtin_fmaf(xv.w, u.w, d1b);
        d2a = __builtin_fmaf(xv.x, w.x, d2a); d2b = __builtin_fmaf(xv.y, w.y, d2b);
        d2a = __builtin_fmaf(xv.z, w.z, d2a); d2b = __builtin_fmaf(xv.w, w.w, d2b);
    }
    float a1 = (d1a + d1b) + c2n[k1];
    float a2 = (d2a + d2b) + c2n[k2];
    int kf = beats(a1, k1, a2, k2) ? k1 : k2;

    out[p] = (float)kf;
    const float4* cf = (const float4*)(cb + (size_t)kf * DDIM);
    float4* qo = (float4*)(out + NPTS + (size_t)p * DDIM);
#pragma unroll
    for (int j = 0; j < 16; ++j) qo[j] = cf[j];
}

extern "C" void kernel_launch(void* const* d_in, const int* in_sizes, int n_in,
                              void* d_out, int out_size, void* d_ws, size_t ws_size,
                              hipStream_t stream) {
    const float* x = (const float*)d_in[0];
    const float* cb = (const float*)d_in[1];
    float* c2n = (float*)d_ws;                                      // 4 KB
    unsigned short* G = (unsigned short*)((char*)d_ws + 4096);      // 256 KB image

    hipLaunchKernelGGL(c2n_kernel, dim3(KCB / 256), dim3(256), 0, stream, cb, c2n);
    hipLaunchKernelGGL(pack_kernel, dim3(KCB * 8 / 256), dim3(256), 0, stream, cb, G);
    hipLaunchKernelGGL(vq_main, dim3(NPTS / 256), dim3(256), 0, stream,
                       x, cb, c2n, G, (float*)d_out);
}

// Round 5
// 163.035 us; speedup vs baseline: 3.8649x; 1.0369x over previous
//
#include <hip/hip_runtime.h>
#include <hip/hip_bf16.h>

#define NPTS 262144
#define DDIM 64
#define KCB  1024
#define CHUNK 128            // codebook rows per staged chunk
#define NCHUNK (KCB / CHUNK) // 8
#define GPC (CHUNK / 16)     // 8 groups (16 cols) per chunk

typedef __attribute__((ext_vector_type(8))) short short8;
typedef __attribute__((ext_vector_type(4))) float f32x4;

static __device__ __forceinline__ unsigned short f2bf_rne(float f) {
    union { float f; unsigned u; } v; v.f = f;
    unsigned r = v.u + 0x7FFFu + ((v.u >> 16) & 1u);
    return (unsigned short)(r >> 16);
}
static __device__ __forceinline__ float bf2f(unsigned short h) {
    union { unsigned u; float f; } v; v.u = ((unsigned)h) << 16;
    return v.f;
}
static __device__ __forceinline__ bool beats(float sa, int ka, float sb, int kb) {
    return (sa > sb) || (sa == sb && ka < kb);
}

// prep 1: c2n[k] = 256 - 0.5*||c||^2  (shift makes all scores positive ->
// f32 bit pattern is monotone as u32; argmax acc == argmin distance)
__global__ __launch_bounds__(256) void c2n_kernel(const float* __restrict__ cb,
                                                  float* __restrict__ c2n) {
    int k = blockIdx.x * blockDim.x + threadIdx.x;
    if (k >= KCB) return;
    const float4* row = (const float4*)(cb + (size_t)k * DDIM);
    float s0 = 0.f, s1 = 0.f, s2 = 0.f, s3 = 0.f;
#pragma unroll
    for (int j = 0; j < DDIM / 4; ++j) {
        float4 a = row[j];
        s0 = __builtin_fmaf(a.x, a.x, s0);
        s1 = __builtin_fmaf(a.y, a.y, s1);
        s2 = __builtin_fmaf(a.z, a.z, s2);
        s3 = __builtin_fmaf(a.w, a.w, s3);
    }
    c2n[k] = 256.0f - 0.5f * ((s0 + s1) + (s2 + s3));
}

// prep 2: pack codebook into bf16 hi/lo fragment-layout image (see r4 notes).
// Chunk c: ushort[16384] = [hi 8192][lo 8192];
// idx = g*1024 + ks*512 + q*128 + col*8 + j  (row = c*128+g*16+col, d = ks*32+q*8+j)
__global__ __launch_bounds__(256) void pack_kernel(const float* __restrict__ cb,
                                                   unsigned short* __restrict__ G) {
    int t = blockIdx.x * 256 + threadIdx.x;  // 8192 threads: (row, d8)
    int r = t >> 3, d8 = t & 7;
    const float4* src = (const float4*)(cb + (size_t)r * DDIM + d8 * 8);
    float4 v0 = src[0], v1 = src[1];
    float vv[8] = {v0.x, v0.y, v0.z, v0.w, v1.x, v1.y, v1.z, v1.w};
    short8 h, l;
#pragma unroll
    for (int j = 0; j < 8; ++j) {
        unsigned short hb = f2bf_rne(vv[j]);
        h[j] = (short)hb;
        l[j] = (short)f2bf_rne(vv[j] - bf2f(hb));
    }
    int c = r >> 7, g = (r >> 4) & 7, col = r & 15;
    int ks = d8 >> 2, q = d8 & 3;
    size_t base = (size_t)c * 16384 + g * 1024 + ks * 512 + q * 128 + col * 8;
    *(short8*)(G + base) = h;
    *(short8*)(G + base + 8192) = l;
}

__global__ __launch_bounds__(256, 2) void vq_main(const float* __restrict__ x,
                                                  const float* __restrict__ cb,
                                                  const float* __restrict__ c2n,
                                                  const unsigned short* __restrict__ G,
                                                  float* __restrict__ out) {
    __shared__ unsigned short frag[2][CHUNK * DDIM * 2];  // 2 x 32KB double buffer
    __shared__ int lds_bk1[256];
    __shared__ int lds_bk2[256];

    const int tid = threadIdx.x;
    const int lane = tid & 63;
    const int wave = tid >> 6;
    const int b15 = lane & 15;
    const int q = lane >> 4;
    const int blk_base = blockIdx.x * 256;
    const int wave_base = blk_base + wave * 64;
    const int lane_off = lane * 16;  // byte offset of this lane's B-fragment slot

    // ---- A fragments (hi/lo bf16 of this wave's 64 points), resident ----
    short8 Ahi[4][2], Alo[4][2];
#pragma unroll
    for (int t = 0; t < 4; ++t) {
        const float* xr = x + (size_t)(wave_base + t * 16 + b15) * DDIM + q * 8;
#pragma unroll
        for (int ks = 0; ks < 2; ++ks) {
            float4 v0 = *(const float4*)(xr + ks * 32);
            float4 v1 = *(const float4*)(xr + ks * 32 + 4);
            float vv[8] = {v0.x, v0.y, v0.z, v0.w, v1.x, v1.y, v1.z, v1.w};
            short8 h, l;
#pragma unroll
            for (int j = 0; j < 8; ++j) {
                unsigned short hb = f2bf_rne(vv[j]);
                h[j] = (short)hb;
                l[j] = (short)f2bf_rne(vv[j] - bf2f(hb));
            }
            Ahi[t][ks] = h;
            Alo[t][ks] = l;
        }
    }

    // packed-key top-2 per point; keys positive-f32 bits, low 6 bits = 63-group
    unsigned int b1[16], b2[16];
#pragma unroll
    for (int i = 0; i < 16; ++i) { b1[i] = 0u; b2[i] = 0u; }

    // stage helper: 8 x 16B global_load_lds per thread = 32KB/block
#define STAGE(cc, buf)                                                                     \
    {                                                                                      \
        const unsigned char* gsrc =                                                        \
            (const unsigned char*)G + (size_t)(cc) * 32768 + wave * 1024 + lane * 16;      \
        unsigned char* ldst = (unsigned char*)&frag[buf][0] + wave * 1024;                 \
        _Pragma("unroll") for (int it = 0; it < 8; ++it)                                   \
            __builtin_amdgcn_global_load_lds(                                              \
                (const __attribute__((address_space(1))) unsigned int*)(gsrc + it * 4096), \
                (__attribute__((address_space(3))) unsigned int*)(ldst + it * 4096),       \
                16, 0, 0);                                                                 \
    }

    // ---- prologue: stage chunk 0; preload its c2n slice ----
    float c2v[GPC], c2vn[GPC];
    STAGE(0, 0);
#pragma unroll
    for (int g = 0; g < GPC; ++g) c2v[g] = c2n[g * 16 + b15];
    __syncthreads();  // drains vmcnt -> buf0 valid

    for (int c = 0; c < NCHUNK; ++c) {
        const int cur = c & 1;
        // phase A: issue next chunk's loads into the other buffer (flies under compute)
        if (c + 1 < NCHUNK) {
            STAGE(c + 1, cur ^ 1);
#pragma unroll
            for (int g = 0; g < GPC; ++g) c2vn[g] = c2n[(c + 1) * CHUNK + g * 16 + b15];
        }
        const unsigned char* fb = (const unsigned char*)&frag[cur][0];

        // phase B: compute 8 groups from current buffer
#pragma unroll
        for (int g = 0; g < GPC; ++g) {
            f32x4 acc[4];
#pragma unroll
            for (int t = 0; t < 4; ++t) acc[t] = (f32x4){c2v[g], c2v[g], c2v[g], c2v[g]};
            __builtin_amdgcn_s_setprio(1);
#pragma unroll
            for (int ks = 0; ks < 2; ++ks) {
                const short8 Bhi = *(const short8*)(fb + g * 2048 + ks * 1024 + lane_off);
                const short8 Blo = *(const short8*)(fb + 16384 + g * 2048 + ks * 1024 + lane_off);
#pragma unroll
                for (int t = 0; t < 4; ++t) {
                    acc[t] = __builtin_amdgcn_mfma_f32_16x16x32_bf16(Ahi[t][ks], Bhi, acc[t], 0, 0, 0);
                    acc[t] = __builtin_amdgcn_mfma_f32_16x16x32_bf16(Ahi[t][ks], Blo, acc[t], 0, 0, 0);
                    acc[t] = __builtin_amdgcn_mfma_f32_16x16x32_bf16(Alo[t][ks], Bhi, acc[t], 0, 0, 0);
                }
            }
            __builtin_amdgcn_s_setprio(0);
            const unsigned int inv = 63u - (unsigned)(c * GPC + g);
#pragma unroll
            for (int t = 0; t < 4; ++t) {
#pragma unroll
                for (int r = 0; r < 4; ++r) {
                    int i = t * 4 + r;
                    unsigned int kb = (__float_as_uint(acc[t][r]) & 0xFFFFFFC0u) | inv;
                    unsigned int mn = b1[i] < kb ? b1[i] : kb;
                    b1[i] = b1[i] > kb ? b1[i] : kb;
                    b2[i] = b2[i] > mn ? b2[i] : mn;
                }
            }
        }
#pragma unroll
        for (int g = 0; g < GPC; ++g) c2v[g] = c2vn[g];
        // single barrier per chunk; its vmcnt drain is free (loads landed under compute)
        __syncthreads();
    }
#undef STAGE

    // ---- decode candidate k before cross-lane merge ----
    unsigned int K1[16], K2[16];
    int I1[16], I2[16];
#pragma unroll
    for (int i = 0; i < 16; ++i) {
        K1[i] = b1[i]; I1[i] = (int)(63u - (b1[i] & 63u)) * 16 + b15;
        K2[i] = b2[i]; I2[i] = (int)(63u - (b2[i] & 63u)) * 16 + b15;
    }
    // merge top-2 across the 16 col-lanes of each quadrant
#pragma unroll
    for (int m = 1; m < 16; m <<= 1) {
#pragma unroll
        for (int i = 0; i < 16; ++i) {
            unsigned int o1 = __shfl_xor(K1[i], m); int oi1 = __shfl_xor(I1[i], m);
            unsigned int o2 = __shfl_xor(K2[i], m); int oi2 = __shfl_xor(I2[i], m);
            bool ob = (o1 > K1[i]) || (o1 == K1[i] && oi1 < I1[i]);
            unsigned int nk1, nk2; int ni1, ni2;
            if (ob) {
                nk1 = o1; ni1 = oi1;
                bool sb = (K1[i] > o2) || (K1[i] == o2 && I1[i] < oi2);
                nk2 = sb ? K1[i] : o2; ni2 = sb ? I1[i] : oi2;
            } else {
                nk1 = K1[i]; ni1 = I1[i];
                bool sb = (o1 > K2[i]) || (o1 == K2[i] && oi1 < I2[i]);
                nk2 = sb ? o1 : K2[i]; ni2 = sb ? oi1 : I2[i];
            }
            K1[i] = nk1; I1[i] = ni1; K2[i] = nk2; I2[i] = ni2;
        }
    }

    if (b15 == 0) {
#pragma unroll
        for (int t = 0; t < 4; ++t)
#pragma unroll
            for (int r = 0; r < 4; ++r) {
                int pl = wave * 64 + t * 16 + q * 4 + r;
                lds_bk1[pl] = I1[t * 4 + r];
                lds_bk2[pl] = I2[t * 4 + r];
            }
    }
    __syncthreads();

    // ---- exact f32 re-rank of the two candidates + output (proven) ----
    const int p = blk_base + tid;
    const int k1 = lds_bk1[tid], k2 = lds_bk2[tid];
    const float4* xr = (const float4*)(x + (size_t)p * DDIM);
    const float4* c1 = (const float4*)(cb + (size_t)k1 * DDIM);
    const float4* c2r = (const float4*)(cb + (size_t)k2 * DDIM);
    float d1a = 0.f, d1b = 0.f, d2a = 0.f, d2b = 0.f;
#pragma unroll
    for (int j = 0; j < 16; ++j) {
        float4 xv = xr[j];
        float4 u = c1[j], w = c2r[j];
        d1a = __builtin_fmaf(xv.x, u.x, d1a); d1b = __builtin_fmaf(xv.y, u.y, d1b);
        d1a = __builtin_fmaf(xv.z, u.z, d1a); d1b = __builtin_fmaf(xv.w, u.w, d1b);
        d2a = __builtin_fmaf(xv.x, w.x, d2a); d2b = __builtin_fmaf(xv.y, w.y, d2b);
        d2a = __builtin_fmaf(xv.z, w.z, d2a); d2b = __builtin_fmaf(xv.w, w.w, d2b);
    }
    float a1 = (d1a + d1b) + c2n[k1];
    float a2 = (d2a + d2b) + c2n[k2];
    int kf = beats(a1, k1, a2, k2) ? k1 : k2;

    out[p] = (float)kf;
    const float4* cf = (const float4*)(cb + (size_t)kf * DDIM);
    float4* qo = (float4*)(out + NPTS + (size_t)p * DDIM);
#pragma unroll
    for (int j = 0; j < 16; ++j) qo[j] = cf[j];
}

extern "C" void kernel_launch(void* const* d_in, const int* in_sizes, int n_in,
                              void* d_out, int out_size, void* d_ws, size_t ws_size,
                              hipStream_t stream) {
    const float* x = (const float*)d_in[0];
    const float* cb = (const float*)d_in[1];
    float* c2n = (float*)d_ws;                                      // 4 KB
    unsigned short* G = (unsigned short*)((char*)d_ws + 4096);      // 256 KB image

    hipLaunchKernelGGL(c2n_kernel, dim3(KCB / 256), dim3(256), 0, stream, cb, c2n);
    hipLaunchKernelGGL(pack_kernel, dim3(KCB * 8 / 256), dim3(256), 0, stream, cb, G);
    hipLaunchKernelGGL(vq_main, dim3(NPTS / 256), dim3(256), 0, stream,
                       x, cb, c2n, G, (float*)d_out);
}

// Round 6
// 142.016 us; speedup vs baseline: 4.4369x; 1.1480x over previous
//
#include <hip/hip_runtime.h>
#include <hip/hip_bf16.h>

#define NPTS 262144
#define DDIM 64
#define KCB  1024
#define CHUNK 64             // codebook rows per staged chunk (16 KB image)
#define NCHUNK (KCB / CHUNK) // 16
#define GPC (CHUNK / 16)     // 4 groups (16 cols) per chunk
#define PPB 256              // points per block (512 threads, 8 waves x 32 pts)

typedef __attribute__((ext_vector_type(8))) short short8;
typedef __attribute__((ext_vector_type(4))) float f32x4;

static __device__ __forceinline__ unsigned short f2bf_rne(float f) {
    union { float f; unsigned u; } v; v.f = f;
    unsigned r = v.u + 0x7FFFu + ((v.u >> 16) & 1u);
    return (unsigned short)(r >> 16);
}
static __device__ __forceinline__ float bf2f(unsigned short h) {
    union { unsigned u; float f; } v; v.u = ((unsigned)h) << 16;
    return v.f;
}
static __device__ __forceinline__ bool beats(float sa, int ka, float sb, int kb) {
    return (sa > sb) || (sa == sb && ka < kb);
}
static __device__ __forceinline__ float keyf(float acc, unsigned inv) {
    return __uint_as_float((__float_as_uint(acc) & 0xFFFFFFC0u) | inv);  // v_and_or_b32
}

// prep 1: c2n[k] = 256 - 0.5*||c||^2 (all scores positive -> float cmp == u32 cmp)
__global__ __launch_bounds__(256) void c2n_kernel(const float* __restrict__ cb,
                                                  float* __restrict__ c2n) {
    int k = blockIdx.x * blockDim.x + threadIdx.x;
    if (k >= KCB) return;
    const float4* row = (const float4*)(cb + (size_t)k * DDIM);
    float s0 = 0.f, s1 = 0.f, s2 = 0.f, s3 = 0.f;
#pragma unroll
    for (int j = 0; j < DDIM / 4; ++j) {
        float4 a = row[j];
        s0 = __builtin_fmaf(a.x, a.x, s0);
        s1 = __builtin_fmaf(a.y, a.y, s1);
        s2 = __builtin_fmaf(a.z, a.z, s2);
        s3 = __builtin_fmaf(a.w, a.w, s3);
    }
    c2n[k] = 256.0f - 0.5f * ((s0 + s1) + (s2 + s3));
}

// prep 2: pack codebook into bf16 hi/lo fragment-layout image, 16KB chunks.
// Chunk c (64 rows): ushort[8192] = [hi 4096][lo 4096];
// idx = g*1024 + ks*512 + q*128 + col*8 + j  (row = c*64+g*16+col, d = ks*32+q*8+j)
__global__ __launch_bounds__(256) void pack_kernel(const float* __restrict__ cb,
                                                   unsigned short* __restrict__ G) {
    int t = blockIdx.x * 256 + threadIdx.x;  // 8192 threads: (row, d8)
    int r = t >> 3, d8 = t & 7;
    const float4* src = (const float4*)(cb + (size_t)r * DDIM + d8 * 8);
    float4 v0 = src[0], v1 = src[1];
    float vv[8] = {v0.x, v0.y, v0.z, v0.w, v1.x, v1.y, v1.z, v1.w};
    short8 h, l;
#pragma unroll
    for (int j = 0; j < 8; ++j) {
        unsigned short hb = f2bf_rne(vv[j]);
        h[j] = (short)hb;
        l[j] = (short)f2bf_rne(vv[j] - bf2f(hb));
    }
    int c = r >> 6, g = (r >> 4) & 3, col = r & 15;
    int ks = d8 >> 2, q = d8 & 3;
    size_t base = (size_t)c * 8192 + g * 1024 + ks * 512 + q * 128 + col * 8;
    *(short8*)(G + base) = h;
    *(short8*)(G + base + 4096) = l;
}

__global__ __launch_bounds__(512, 4) void vq_main(const float* __restrict__ x,
                                                  const float* __restrict__ cb,
                                                  const float* __restrict__ c2n,
                                                  const unsigned short* __restrict__ G,
                                                  float* __restrict__ out) {
    __shared__ unsigned short frag[2][CHUNK * DDIM * 2];  // 2 x 16KB double buffer
    __shared__ int lds_bk1[PPB];
    __shared__ int lds_bk2[PPB];

    const int tid = threadIdx.x;
    const int lane = tid & 63;
    const int wave = tid >> 6;       // 0..7
    const int b15 = lane & 15;
    const int q = lane >> 4;
    const int blk_base = blockIdx.x * PPB;
    const int wave_base = blk_base + wave * 32;
    const int lane_off = lane * 16;  // byte offset of this lane's B-fragment slot

    // ---- A fragments: 2 point-tiles x 2 ksteps x (hi,lo) = 32 VGPR, resident ----
    short8 Ahi[2][2], Alo[2][2];
#pragma unroll
    for (int t = 0; t < 2; ++t) {
        const float* xr = x + (size_t)(wave_base + t * 16 + b15) * DDIM + q * 8;
#pragma unroll
        for (int ks = 0; ks < 2; ++ks) {
            float4 v0 = *(const float4*)(xr + ks * 32);
            float4 v1 = *(const float4*)(xr + ks * 32 + 4);
            float vv[8] = {v0.x, v0.y, v0.z, v0.w, v1.x, v1.y, v1.z, v1.w};
            short8 h, l;
#pragma unroll
            for (int j = 0; j < 8; ++j) {
                unsigned short hb = f2bf_rne(vv[j]);
                h[j] = (short)hb;
                l[j] = (short)f2bf_rne(vv[j] - bf2f(hb));
            }
            Ahi[t][ks] = h;
            Alo[t][ks] = l;
        }
    }

    // top-2 keys per point (8 points/lane), positive-float keys, low6 = 63-group
    float b1[8], b2[8];
#pragma unroll
    for (int i = 0; i < 8; ++i) { b1[i] = 0.0f; b2[i] = 0.0f; }

    // stage 16KB chunk: 512 threads x 2 x 16B global_load_lds
#define STAGE(cc, buf)                                                                     \
    {                                                                                      \
        const unsigned char* gsrc = (const unsigned char*)G + (size_t)(cc) * 16384 + tid * 16; \
        unsigned char* ldst = (unsigned char*)&frag[buf][0] + tid * 16;                    \
        _Pragma("unroll") for (int it = 0; it < 2; ++it)                                   \
            __builtin_amdgcn_global_load_lds(                                              \
                (const __attribute__((address_space(1))) unsigned int*)(gsrc + it * 8192), \
                (__attribute__((address_space(3))) unsigned int*)(ldst + it * 8192),       \
                16, 0, 0);                                                                 \
    }

    float c2v[GPC], c2vn[GPC];
    STAGE(0, 0);
#pragma unroll
    for (int g = 0; g < GPC; ++g) c2v[g] = c2n[g * 16 + b15];
    __syncthreads();  // drains vmcnt -> buf0 valid

    for (int c = 0; c < NCHUNK; ++c) {
        const int cur = c & 1;
        if (c + 1 < NCHUNK) {
            STAGE(c + 1, cur ^ 1);
#pragma unroll
            for (int g = 0; g < GPC; ++g) c2vn[g] = c2n[(c + 1) * CHUNK + g * 16 + b15];
        }
        const unsigned char* fb = (const unsigned char*)&frag[cur][0];

        // 2 group-pairs per chunk; paired top-2 update (max3 + med3)
#pragma unroll
        for (int gp = 0; gp < 2; ++gp) {
            const int g0 = gp * 2, g1 = g0 + 1;
            const unsigned inv0 = 63u - (unsigned)(c * GPC + g0);

            f32x4 acc0[2];
#pragma unroll
            for (int t = 0; t < 2; ++t) acc0[t] = (f32x4){c2v[g0], c2v[g0], c2v[g0], c2v[g0]};
            __builtin_amdgcn_s_setprio(1);
#pragma unroll
            for (int ks = 0; ks < 2; ++ks) {
                const short8 Bhi = *(const short8*)(fb + g0 * 2048 + ks * 1024 + lane_off);
                const short8 Blo = *(const short8*)(fb + 8192 + g0 * 2048 + ks * 1024 + lane_off);
#pragma unroll
                for (int t = 0; t < 2; ++t) {
                    acc0[t] = __builtin_amdgcn_mfma_f32_16x16x32_bf16(Ahi[t][ks], Bhi, acc0[t], 0, 0, 0);
                    acc0[t] = __builtin_amdgcn_mfma_f32_16x16x32_bf16(Ahi[t][ks], Blo, acc0[t], 0, 0, 0);
                    acc0[t] = __builtin_amdgcn_mfma_f32_16x16x32_bf16(Alo[t][ks], Bhi, acc0[t], 0, 0, 0);
                }
            }
            __builtin_amdgcn_s_setprio(0);
            float ka[8];
#pragma unroll
            for (int t = 0; t < 2; ++t)
#pragma unroll
                for (int r = 0; r < 4; ++r) ka[t * 4 + r] = keyf(acc0[t][r], inv0);

            f32x4 acc1[2];
#pragma unroll
            for (int t = 0; t < 2; ++t) acc1[t] = (f32x4){c2v[g1], c2v[g1], c2v[g1], c2v[g1]};
            __builtin_amdgcn_s_setprio(1);
#pragma unroll
            for (int ks = 0; ks < 2; ++ks) {
                const short8 Bhi = *(const short8*)(fb + g1 * 2048 + ks * 1024 + lane_off);
                const short8 Blo = *(const short8*)(fb + 8192 + g1 * 2048 + ks * 1024 + lane_off);
#pragma unroll
                for (int t = 0; t < 2; ++t) {
                    acc1[t] = __builtin_amdgcn_mfma_f32_16x16x32_bf16(Ahi[t][ks], Bhi, acc1[t], 0, 0, 0);
                    acc1[t] = __builtin_amdgcn_mfma_f32_16x16x32_bf16(Ahi[t][ks], Blo, acc1[t], 0, 0, 0);
                    acc1[t] = __builtin_amdgcn_mfma_f32_16x16x32_bf16(Alo[t][ks], Bhi, acc1[t], 0, 0, 0);
                }
            }
            __builtin_amdgcn_s_setprio(0);
#pragma unroll
            for (int t = 0; t < 2; ++t)
#pragma unroll
                for (int r = 0; r < 4; ++r) {
                    const int i = t * 4 + r;
                    const float kb = keyf(acc1[t][r], inv0 - 1u);
                    // top-2 of {b1, ka, kb} = {max3, med3}; b2' = max(b2, med3)
                    const float med = __builtin_amdgcn_fmed3f(b1[i], ka[i], kb);
                    float nb1;
                    asm("v_max3_f32 %0, %1, %2, %3" : "=v"(nb1) : "v"(b1[i]), "v"(ka[i]), "v"(kb));
                    b1[i] = nb1;
                    b2[i] = fmaxf(b2[i], med);
                }
        }
#pragma unroll
        for (int g = 0; g < GPC; ++g) c2v[g] = c2vn[g];
        __syncthreads();
    }
#undef STAGE

    // ---- decode candidate k, then merge top-2 across the 16 col-lanes ----
    unsigned int K1[8], K2[8];
    int I1[8], I2[8];
#pragma unroll
    for (int i = 0; i < 8; ++i) {
        K1[i] = __float_as_uint(b1[i]); I1[i] = (int)(63u - (K1[i] & 63u)) * 16 + b15;
        K2[i] = __float_as_uint(b2[i]); I2[i] = (int)(63u - (K2[i] & 63u)) * 16 + b15;
    }
#pragma unroll
    for (int m = 1; m < 16; m <<= 1) {
#pragma unroll
        for (int i = 0; i < 8; ++i) {
            unsigned int o1 = __shfl_xor(K1[i], m); int oi1 = __shfl_xor(I1[i], m);
            unsigned int o2 = __shfl_xor(K2[i], m); int oi2 = __shfl_xor(I2[i], m);
            bool ob = (o1 > K1[i]) || (o1 == K1[i] && oi1 < I1[i]);
            unsigned int nk1, nk2; int ni1, ni2;
            if (ob) {
                nk1 = o1; ni1 = oi1;
                bool sb = (K1[i] > o2) || (K1[i] == o2 && I1[i] < oi2);
                nk2 = sb ? K1[i] : o2; ni2 = sb ? I1[i] : oi2;
            } else {
                nk1 = K1[i]; ni1 = I1[i];
                bool sb = (o1 > K2[i]) || (o1 == K2[i] && oi1 < I2[i]);
                nk2 = sb ? o1 : K2[i]; ni2 = sb ? oi1 : I2[i];
            }
            K1[i] = nk1; I1[i] = ni1; K2[i] = nk2; I2[i] = ni2;
        }
    }

    if (b15 == 0) {
#pragma unroll
        for (int t = 0; t < 2; ++t)
#pragma unroll
            for (int r = 0; r < 4; ++r) {
                int pl = wave * 32 + t * 16 + q * 4 + r;
                lds_bk1[pl] = I1[t * 4 + r];
                lds_bk2[pl] = I2[t * 4 + r];
            }
    }
    __syncthreads();

    // ---- exact f32 re-rank: 2 threads per point, one candidate each ----
    const int pid = tid >> 1;
    const int p = blk_base + pid;
    const int ksel = (tid & 1) ? lds_bk2[pid] : lds_bk1[pid];
    const float4* xr = (const float4*)(x + (size_t)p * DDIM);
    const float4* cr = (const float4*)(cb + (size_t)ksel * DDIM);
    float da = 0.f, db = 0.f;
#pragma unroll
    for (int j = 0; j < 16; ++j) {
        float4 xv = xr[j];
        float4 u = cr[j];
        da = __builtin_fmaf(xv.x, u.x, da); db = __builtin_fmaf(xv.y, u.y, db);
        da = __builtin_fmaf(xv.z, u.z, da); db = __builtin_fmaf(xv.w, u.w, db);
    }
    float a = (da + db) + c2n[ksel];
    float oa = __shfl_xor(a, 1);
    int ok = __shfl_xor(ksel, 1);
    const bool first = ((tid & 1) == 0);
    float a1 = first ? a : oa; int k1 = first ? ksel : ok;
    float a2 = first ? oa : a; int k2 = first ? ok : ksel;
    int kf = beats(a1, k1, a2, k2) ? k1 : k2;

    if (first) out[p] = (float)kf;
    const float4* cf = (const float4*)(cb + (size_t)kf * DDIM + (tid & 1) * 32);
    float4* qo = (float4*)(out + NPTS + (size_t)p * DDIM + (tid & 1) * 32);
#pragma unroll
    for (int j = 0; j < 8; ++j) qo[j] = cf[j];
}

extern "C" void kernel_launch(void* const* d_in, const int* in_sizes, int n_in,
                              void* d_out, int out_size, void* d_ws, size_t ws_size,
                              hipStream_t stream) {
    const float* x = (const float*)d_in[0];
    const float* cb = (const float*)d_in[1];
    float* c2n = (float*)d_ws;                                      // 4 KB
    unsigned short* G = (unsigned short*)((char*)d_ws + 4096);      // 256 KB image

    hipLaunchKernelGGL(c2n_kernel, dim3(KCB / 256), dim3(256), 0, stream, cb, c2n);
    hipLaunchKernelGGL(pack_kernel, dim3(KCB * 8 / 256), dim3(256), 0, stream, cb, G);
    hipLaunchKernelGGL(vq_main, dim3(NPTS / PPB), dim3(512), 0, stream,
                       x, cb, c2n, G, (float*)d_out);
}